// Round 11
// baseline (90.770 us; speedup 1.0000x reference)
//
#include <hip/hip_runtime.h>
#include <cstddef>
#include <cstdint>

// Problem constants: T=2048, B=8, C=1024, H=16, K=31, P=15
constexpr int T_ = 2048;
constexpr int B_ = 8;
constexpr int C_ = 1024;
constexpr int H_ = 16;
constexpr int K_ = 31;
constexpr int P_ = 15;
constexpr int M_ = T_ * B_;   // 16384
constexpr int N_ = H_ * K_;   // 496
constexpr int NP = 512;       // padded N, slot layout n' = h*32 + k

typedef _Float16 f16x4 __attribute__((ext_vector_type(4)));
typedef _Float16 f16x8 __attribute__((ext_vector_type(8)));
typedef float f32x4 __attribute__((ext_vector_type(4)));

__device__ __forceinline__ void async_cp16(const void* g, void* l) {
    __builtin_amdgcn_global_load_lds(
        (const __attribute__((address_space(1))) void*)g,
        (__attribute__((address_space(3))) void*)l, 16, 0, 0);
}

// ---------------------------------------------------------------------------
// K0: W (496x1024 f32) -> Wh (512x1024 fp16, slot layout n'=h*32+k, k==31
// rows zero). 2 MB read -> ~2 us. X is NOT converted (GEMM reads f32 X).
// ---------------------------------------------------------------------------
__global__ __launch_bounds__(256)
void cvt_w(const float* __restrict__ W, _Float16* __restrict__ Wh) {
    const int j = blockIdx.x * 256 + threadIdx.x;   // chunk id, 65536 total
    const int n = j >> 7, sp = j & 127;
    const int h = n >> 5, k = n & 31;
    f16x8 hv = {};
    if (k < 31) {
        const float* wp = W + (size_t)(h * 31 + k) * C_ + sp * 8;
        const float4 v0 = *(const float4*)(wp);
        const float4 v1 = *(const float4*)(wp + 4);
        hv[0] = (_Float16)v0.x; hv[1] = (_Float16)v0.y;
        hv[2] = (_Float16)v0.z; hv[3] = (_Float16)v0.w;
        hv[4] = (_Float16)v1.x; hv[5] = (_Float16)v1.y;
        hv[6] = (_Float16)v1.z; hv[7] = (_Float16)v1.w;
    }
    *(f16x8*)(Wh + (size_t)n * C_ + sp * 8) = hv;
}

// ---------------------------------------------------------------------------
// K1: GEMM (logits = X*W^T) + softmax -> WSM fp16.
// BM=BN=128, BK=64, 256 thr (4 waves 2x2, wave tile 64x64).
// A: f32 X -> regs (issue-early) -> f16 swizzled ds_write (write-late),
//    2-deep LDS buffers.
// B: global_load_lds, 3-deep, counted vmcnt (4 glds in flight at barrier).
// LDS 80 KB -> 2 blocks/CU. Ls logits overlay for the softmax epilogue.
// ---------------------------------------------------------------------------
__global__ __launch_bounds__(256)
void gemm_softmax(const float* __restrict__ X, const _Float16* __restrict__ Wh,
                  _Float16* __restrict__ WSM) {
    __shared__ union {
        struct { _Float16 A[2][128 * 64]; _Float16 B[3][128 * 64]; } s;  // 80 KB
        _Float16 Ls[128 * 136];   // 34.8 KB overlay (phase-disjoint)
    } u;

    const int tid = threadIdx.x;
    const int lane = tid & 63;
    const int w = tid >> 6;
    const int wm = (w >> 1) * 64;
    const int wn = (w & 1) * 64;
    const int col = lane & 15;
    const int g = lane >> 4;
    const int m0 = blockIdx.x * 128;
    const int n0 = blockIdx.y * 128;

    // ---- A staging map: thread -> row ar = tid>>1, 4 chunks cs = acs0+q ----
    const int ar = tid >> 1;
    const int acs0 = (tid & 1) * 4;
    const float* axbase = X + (size_t)(m0 + ar) * C_;

    // ---- B staging map: 4 glds chunks per thread ----
    const _Float16* bsrc[4];
#pragma unroll
    for (int p = 0; p < 4; ++p) {
        const int ci = p * 256 + tid;
        const int r = ci >> 3, cs = ci & 7;
        const int cl = cs ^ (r & 7);
        bsrc[p] = Wh + (size_t)(n0 + r) * C_ + cl * 8;
    }

    f32x4 acc[4][4] = {};
    float4 areg[4][2];

    // A load for k-offset k0 into areg (8 float4 loads)
#define LOAD_A(k0)                                                        \
    _Pragma("unroll")                                                     \
    for (int q = 0; q < 4; ++q) {                                         \
        const int cl = (acs0 + q) ^ (ar & 7);                             \
        const float* src = axbase + (k0) + cl * 8;                        \
        areg[q][0] = *(const float4*)src;                                 \
        areg[q][1] = *(const float4*)(src + 4);                           \
    }
    // A convert + write into buffer buf at store position acs0+q
#define WRITE_A(buf)                                                      \
    _Pragma("unroll")                                                     \
    for (int q = 0; q < 4; ++q) {                                         \
        f16x8 hv;                                                         \
        hv[0] = (_Float16)areg[q][0].x; hv[1] = (_Float16)areg[q][0].y;   \
        hv[2] = (_Float16)areg[q][0].z; hv[3] = (_Float16)areg[q][0].w;   \
        hv[4] = (_Float16)areg[q][1].x; hv[5] = (_Float16)areg[q][1].y;   \
        hv[6] = (_Float16)areg[q][1].z; hv[7] = (_Float16)areg[q][1].w;   \
        *(f16x8*)&u.s.A[buf][ar * 64 + (acs0 + q) * 8] = hv;              \
    }
#define ISSUE_B(k0, buf)                                                  \
    _Pragma("unroll")                                                     \
    for (int p = 0; p < 4; ++p) {                                         \
        const int ci = p * 256 + tid;                                     \
        async_cp16(bsrc[p] + (k0), &u.s.B[buf][ci * 8]);                  \
    }

    // ---- prologue ----
    LOAD_A(0);            // 8 vm
    ISSUE_B(0, 0);        // 4 vm
    ISSUE_B(64, 1);       // 4 vm
    asm volatile("s_waitcnt vmcnt(8)" ::: "memory");   // A(0) done
    WRITE_A(0);
    asm volatile("s_waitcnt vmcnt(4) lgkmcnt(0)" ::: "memory");  // B(0) done
    __builtin_amdgcn_s_barrier();
    __builtin_amdgcn_sched_barrier(0);

    for (int t = 0; t < 16; ++t) {
        const int ca = t & 1, cb = t % 3;
        // ---- issue-early: A(t+1) to regs, B(t+2) to LDS ----
        if (t < 15) { LOAD_A((t + 1) * 64); }
        if (t < 14) { ISSUE_B((t + 2) * 64, (t + 2) % 3); }

        // ---- compute k-step t ----
        f16x8 a[2][4], b[2][4];
#pragma unroll
        for (int kk = 0; kk < 2; ++kk) {
#pragma unroll
            for (int mf = 0; mf < 4; ++mf) {
                const int row = wm + mf * 16 + col;
                const int c = ((kk << 2) | g) ^ (row & 7);
                a[kk][mf] = *(const f16x8*)&u.s.A[ca][row * 64 + c * 8];
            }
#pragma unroll
            for (int nf = 0; nf < 4; ++nf) {
                const int row = wn + nf * 16 + col;
                const int c = ((kk << 2) | g) ^ (row & 7);
                b[kk][nf] = *(const f16x8*)&u.s.B[cb][row * 64 + c * 8];
            }
        }
#pragma unroll
        for (int kk = 0; kk < 2; ++kk)
#pragma unroll
            for (int nf = 0; nf < 4; ++nf)
#pragma unroll
                for (int mf = 0; mf < 4; ++mf)
                    acc[mf][nf] = __builtin_amdgcn_mfma_f32_16x16x32_f16(
                        a[kk][mf], b[kk][nf], acc[mf][nf], 0, 0, 0);

        // ---- write-late: A(t+1); counted wait keeps B(t+2) in flight ----
        if (t < 14) {
            asm volatile("s_waitcnt vmcnt(4)" ::: "memory");  // A(t+1) done
        } else {
            asm volatile("s_waitcnt vmcnt(0)" ::: "memory");
        }
        if (t < 15) { WRITE_A(ca ^ 1); }
        asm volatile("s_waitcnt lgkmcnt(0)" ::: "memory");
        __builtin_amdgcn_s_barrier();
        __builtin_amdgcn_sched_barrier(0);
    }

    // ---- epilogue: logits -> Ls overlay ----
    const int rb = g * 4;
#pragma unroll
    for (int nf = 0; nf < 4; ++nf) {
        const int nl = wn + nf * 16 + col;
#pragma unroll
        for (int mf = 0; mf < 4; ++mf) {
            const int row = wm + mf * 16 + rb;
#pragma unroll
            for (int r = 0; r < 4; ++r)
                u.Ls[(row + r) * 136 + nl] = (_Float16)acc[mf][nf][r];
        }
    }
    __syncthreads();

    // ---- softmax: 512 (row, head-local) tasks, 2 per thread ----
#pragma unroll
    for (int p = 0; p < 2; ++p) {
        const int task = tid + p * 256;
        const int row = task >> 2, hl = task & 3;
        const _Float16* lp = &u.Ls[row * 136 + hl * 32];
        float v[32];
#pragma unroll
        for (int c = 0; c < 4; ++c) {
            const f16x8 ch = *(const f16x8*)(lp + c * 8);
#pragma unroll
            for (int e = 0; e < 8; ++e) v[c * 8 + e] = (float)ch[e];
        }
        float mx = v[0];
#pragma unroll
        for (int k = 1; k < 31; ++k) mx = fmaxf(mx, v[k]);
        float ssum = 0.f;
#pragma unroll
        for (int k = 0; k < 31; ++k) { v[k] = __expf(v[k] - mx); ssum += v[k]; }
        const float inv = 1.f / ssum;
        _Float16* op = WSM + (size_t)(m0 + row) * NP + n0 + hl * 32;
#pragma unroll
        for (int c = 0; c < 4; ++c) {
            f16x8 ov;
#pragma unroll
            for (int e = 0; e < 8; ++e) {
                const int k = c * 8 + e;
                ov[e] = (k < 31) ? (_Float16)(v[k] * inv) : (_Float16)0.f;
            }
            *(f16x8*)(op + c * 8) = ov;
        }
    }
#undef LOAD_A
#undef WRITE_A
#undef ISSUE_B
}

// ---------------------------------------------------------------------------
// K2: depthwise dynamic conv, x read as f32 X (L3-resident after GEMM).
// Block = 64 t x one (b,h). xs[94][64] f32, 16B-chunk XOR swizzle (row&7);
// ws[64][36] f32. 32.5 KB LDS -> high occupancy.
// ---------------------------------------------------------------------------
__global__ __launch_bounds__(256)
void dconv(const float* __restrict__ X, const _Float16* __restrict__ WSM,
           float* __restrict__ out) {
    __shared__ float xs[94][64];
    __shared__ float ws[64][36];

    const int tid = threadIdx.x;
    const int t0 = blockIdx.x * 64;
    const int bh = (int)blockIdx.y;
    const int b = bh >> 4, h = bh & 15;

    // stage x window rows t0-15 .. t0+78 (swizzled 16B chunks, f32 direct)
    for (int task = tid; task < 94 * 16; task += 256) {
        const int r = task >> 4, sc = task & 15;
        const int tp = t0 + r - 15;
        f32x4 v = {};
        if (tp >= 0 && tp < T_)
            v = *(const f32x4*)(X + ((size_t)tp * B_ + b) * C_ + h * 64 + sc * 4);
        *(f32x4*)&xs[r][(sc ^ (r & 7)) * 4] = v;
    }
    // stage softmaxed weights (fp16 -> f32), vectorized
    {
        const int t = tid >> 2, kc = (tid & 3) * 8;
        const f16x8 wv =
            *(const f16x8*)(WSM + ((size_t)(t0 + t) * B_ + b) * NP + h * 32 + kc);
        f32x4 lo, hi;
        lo[0] = (float)wv[0]; lo[1] = (float)wv[1];
        lo[2] = (float)wv[2]; lo[3] = (float)wv[3];
        hi[0] = (float)wv[4]; hi[1] = (float)wv[5];
        hi[2] = (float)wv[6]; hi[3] = (float)wv[7];
        *(f32x4*)&ws[t][kc] = lo;
        *(f32x4*)&ws[t][kc + 4] = hi;
    }
    __syncthreads();

    const int s = tid & 15;
    const int tg4 = (tid >> 4) * 4;
    f32x4 acc[4] = {};
    f32x4 wc[4];

#pragma unroll
    for (int rr = 0; rr < 34; ++rr) {
        const int r = tg4 + rr;
        const f32x4 xv = *(const f32x4*)&xs[r][(s ^ (r & 7)) * 4];
#pragma unroll
        for (int i = 0; i < 4; ++i) {
            const int k = rr - i;
            if (k < 0 || k > 30) continue;
            if ((k & 3) == 0) wc[i] = *(const f32x4*)&ws[tg4 + i][k];
            acc[i] += wc[i][k & 3] * xv;
        }
    }

#pragma unroll
    for (int i = 0; i < 4; ++i) {
        const int t = t0 + tg4 + i;
        *(f32x4*)(out + ((size_t)t * B_ + b) * C_ + h * 64 + s * 4) = acc[i];
    }
}

// ---------------------------------------------------------------------------
extern "C" void kernel_launch(void* const* d_in, const int* in_sizes, int n_in,
                              void* d_out, int out_size, void* d_ws,
                              size_t ws_size, hipStream_t stream) {
    const float* X = (const float*)d_in[0];
    const float* W = (const float*)d_in[1];
    float* out = (float*)d_out;

    // workspace: Wh (1 MiB) | WSM (16 MiB)
    _Float16* Wh = (_Float16*)d_ws;
    _Float16* WSM = (_Float16*)((char*)d_ws + (size_t)NP * C_ * 2);

    cvt_w<<<256, 256, 0, stream>>>(W, Wh);
    gemm_softmax<<<dim3(M_ / 128, NP / 128), 256, 0, stream>>>(X, Wh, WSM);
    dconv<<<dim3(T_ / 64, B_ * H_), 256, 0, stream>>>(X, WSM, out);
}

// Round 12
// 76.021 us; speedup vs baseline: 1.1940x; 1.1940x over previous
//
#include <hip/hip_runtime.h>
#include <cstddef>
#include <cstdint>

// Problem constants: T=2048, B=8, C=1024, H=16, K=31, P=15
constexpr int T_ = 2048;
constexpr int B_ = 8;
constexpr int C_ = 1024;
constexpr int H_ = 16;
constexpr int K_ = 31;
constexpr int P_ = 15;
constexpr int M_ = T_ * B_;   // 16384
constexpr int N_ = H_ * K_;   // 496
constexpr int NP = 512;       // padded N, slot layout n' = h*32 + k

typedef _Float16 f16x4 __attribute__((ext_vector_type(4)));
typedef _Float16 f16x8 __attribute__((ext_vector_type(8)));
typedef float f32x4 __attribute__((ext_vector_type(4)));

__device__ __forceinline__ void async_cp16(const void* g, void* l) {
    __builtin_amdgcn_global_load_lds(
        (const __attribute__((address_space(1))) void*)g,
        (__attribute__((address_space(3))) void*)l, 16, 0, 0);
}

// ---------------------------------------------------------------------------
// K0: fused convert. X -> Xh fp16; W -> Wh (512x1024 fp16, slot layout
// n' = h*32+k; k==31 rows zero). Identical to round 8.
// ---------------------------------------------------------------------------
constexpr int XCH = M_ * C_ / 8;    // 2,097,152 f16x8 chunks
constexpr int WCH = NP * C_ / 8;    // 65,536

__global__ __launch_bounds__(256)
void cvt_inputs(const float* __restrict__ X, const float* __restrict__ W,
                _Float16* __restrict__ Xh, _Float16* __restrict__ Wh) {
    const int id = blockIdx.x * 256 + threadIdx.x;
    if (id < XCH) {
        const float4 v0 = *(const float4*)(X + (size_t)id * 8);
        const float4 v1 = *(const float4*)(X + (size_t)id * 8 + 4);
        f16x8 hv;
        hv[0] = (_Float16)v0.x; hv[1] = (_Float16)v0.y;
        hv[2] = (_Float16)v0.z; hv[3] = (_Float16)v0.w;
        hv[4] = (_Float16)v1.x; hv[5] = (_Float16)v1.y;
        hv[6] = (_Float16)v1.z; hv[7] = (_Float16)v1.w;
        *(f16x8*)(Xh + (size_t)id * 8) = hv;
    } else {
        const int j = id - XCH;
        const int n = j >> 7, sp = j & 127;
        const int h = n >> 5, k = n & 31;
        f16x8 hv = {};
        if (k < 31) {
            const float* wp = W + (size_t)(h * 31 + k) * C_ + sp * 8;
            const float4 v0 = *(const float4*)(wp);
            const float4 v1 = *(const float4*)(wp + 4);
            hv[0] = (_Float16)v0.x; hv[1] = (_Float16)v0.y;
            hv[2] = (_Float16)v0.z; hv[3] = (_Float16)v0.w;
            hv[4] = (_Float16)v1.x; hv[5] = (_Float16)v1.y;
            hv[6] = (_Float16)v1.z; hv[7] = (_Float16)v1.w;
        }
        *(f16x8*)(Wh + (size_t)n * C_ + sp * 8) = hv;
    }
}

// ---------------------------------------------------------------------------
// K1: GEMM + softmax -> WSM fp16. Round-8 GEMM verbatim (counted vmcnt,
// A 3-deep, B 2-deep, 80 KB LDS, 2 blocks/CU). NEW: in-register shuffle
// softmax epilogue (no Ls overlay): the 31 logits of a (row, head) span the
// 16 lanes of one row-group x 2 nf; 4 shfl_xor rounds reduce max and sum;
// j=31 pad slot masked with -1e30. 2B f16 stores (32B per 16-lane group).
// ---------------------------------------------------------------------------
__global__ __launch_bounds__(256)
void gemm_softmax(const _Float16* __restrict__ Xh,
                  const _Float16* __restrict__ Wh,
                  _Float16* __restrict__ WSM) {
    __shared__ _Float16 As[3][128 * 64];   // 48 KB
    __shared__ _Float16 Bs[2][128 * 64];   // 32 KB

    const int tid = threadIdx.x;
    const int lane = tid & 63;
    const int w = tid >> 6;
    const int wm = (w >> 1) * 64;
    const int wn = (w & 1) * 64;
    const int col = lane & 15;
    const int g = lane >> 4;
    const int m0 = blockIdx.x * 128;
    const int n0 = blockIdx.y * 128;

    const _Float16* asrc[4];
    const _Float16* bsrc[4];
#pragma unroll
    for (int p = 0; p < 4; ++p) {
        const int ci = p * 256 + tid;
        const int r = ci >> 3, cs = ci & 7;
        const int cl = cs ^ (r & 7);
        asrc[p] = Xh + (size_t)(m0 + r) * C_ + cl * 8;
        bsrc[p] = Wh + (size_t)(n0 + r) * C_ + cl * 8;
    }

    f32x4 acc[4][4] = {};

#pragma unroll
    for (int p = 0; p < 4; ++p) {
        const int ci = p * 256 + tid;
        async_cp16(asrc[p], &As[0][ci * 8]);
    }
#pragma unroll
    for (int p = 0; p < 4; ++p) {
        const int ci = p * 256 + tid;
        async_cp16(bsrc[p], &Bs[0][ci * 8]);
    }
#pragma unroll
    for (int p = 0; p < 4; ++p) {
        const int ci = p * 256 + tid;
        async_cp16(asrc[p] + 64, &As[1][ci * 8]);
    }
    asm volatile("s_waitcnt vmcnt(4)" ::: "memory");
    __builtin_amdgcn_s_barrier();
    __builtin_amdgcn_sched_barrier(0);

    for (int t = 0; t < 16; ++t) {
        const int ca = t % 3, cb = t & 1;
        if (t < 15) {
            const int k1 = (t + 1) * 64;
#pragma unroll
            for (int p = 0; p < 4; ++p) {
                const int ci = p * 256 + tid;
                async_cp16(bsrc[p] + k1, &Bs[cb ^ 1][ci * 8]);
            }
        }
        if (t < 14) {
            const int k2 = (t + 2) * 64;
            const int ca2 = (t + 2) % 3;
#pragma unroll
            for (int p = 0; p < 4; ++p) {
                const int ci = p * 256 + tid;
                async_cp16(asrc[p] + k2, &As[ca2][ci * 8]);
            }
        }

        f16x8 a[2][4], b[2][4];
#pragma unroll
        for (int kk = 0; kk < 2; ++kk) {
#pragma unroll
            for (int mf = 0; mf < 4; ++mf) {
                const int row = wm + mf * 16 + col;
                const int c = ((kk << 2) | g) ^ (row & 7);
                a[kk][mf] = *(const f16x8*)&As[ca][row * 64 + c * 8];
            }
#pragma unroll
            for (int nf = 0; nf < 4; ++nf) {
                const int row = wn + nf * 16 + col;
                const int c = ((kk << 2) | g) ^ (row & 7);
                b[kk][nf] = *(const f16x8*)&Bs[cb][row * 64 + c * 8];
            }
        }
        __builtin_amdgcn_s_setprio(1);
#pragma unroll
        for (int kk = 0; kk < 2; ++kk)
#pragma unroll
            for (int nf = 0; nf < 4; ++nf)
#pragma unroll
                for (int mf = 0; mf < 4; ++mf)
                    acc[mf][nf] = __builtin_amdgcn_mfma_f32_16x16x32_f16(
                        a[kk][mf], b[kk][nf], acc[mf][nf], 0, 0, 0);
        __builtin_amdgcn_s_setprio(0);

        if (t < 14) {
            asm volatile("s_waitcnt vmcnt(4)" ::: "memory");
        } else {
            asm volatile("s_waitcnt vmcnt(0)" ::: "memory");
        }
        __builtin_amdgcn_s_barrier();
        __builtin_amdgcn_sched_barrier(0);
    }

    // ---- epilogue: in-register shuffle softmax -> WSM fp16 ----
    // Row r of the block: r = wm + mf*16 + g*4 + ri. Head pair per wn-half:
    // nf 0,1 -> head (wn+0)/32; nf 2,3 -> head (wn+32)/32. j = nf*16+col
    // within the 32-slot head; j==31 (nf odd, col 15) is the zero-pad slot.
    const bool tail = (col == 15);
#pragma unroll
    for (int mf = 0; mf < 4; ++mf) {
#pragma unroll
        for (int ri = 0; ri < 4; ++ri) {
            const int row = wm + mf * 16 + g * 4 + ri;
            const float v0 = acc[mf][0][ri];
            const float v1 = acc[mf][1][ri];
            const float v2 = acc[mf][2][ri];
            const float v3 = acc[mf][3][ri];
            const float u1 = tail ? -1e30f : v1;
            const float u3 = tail ? -1e30f : v3;
            float mA = fmaxf(v0, u1);
            float mB = fmaxf(v2, u3);
#pragma unroll
            for (int d = 1; d < 16; d <<= 1) {
                mA = fmaxf(mA, __shfl_xor(mA, d));
                mB = fmaxf(mB, __shfl_xor(mB, d));
            }
            const float e0 = __expf(v0 - mA);
            const float e1 = tail ? 0.f : __expf(v1 - mA);
            const float e2 = __expf(v2 - mB);
            const float e3 = tail ? 0.f : __expf(v3 - mB);
            float sA = e0 + e1;
            float sB = e2 + e3;
#pragma unroll
            for (int d = 1; d < 16; d <<= 1) {
                sA += __shfl_xor(sA, d);
                sB += __shfl_xor(sB, d);
            }
            const float iA = 1.f / sA;
            const float iB = 1.f / sB;
            _Float16* op = WSM + (size_t)(m0 + row) * NP + n0 + wn + col;
            op[0]  = (_Float16)(e0 * iA);
            op[16] = (_Float16)(e1 * iA);
            op[32] = (_Float16)(e2 * iB);
            op[48] = (_Float16)(e3 * iB);
        }
    }
}

// ---------------------------------------------------------------------------
// K2: depthwise dynamic conv, x read as fp16 (Xh). Identical to round 8.
// ---------------------------------------------------------------------------
__global__ __launch_bounds__(256)
void dconv(const _Float16* __restrict__ Xh, const _Float16* __restrict__ WSM,
           float* __restrict__ out) {
    __shared__ float xs[94][64];
    __shared__ float ws[64][36];

    const int tid = threadIdx.x;
    const int t0 = blockIdx.x * 64;
    const int bh = (int)blockIdx.y;
    const int b = bh >> 4, h = bh & 15;

    for (int task = tid; task < 94 * 8; task += 256) {
        const int r = task >> 3, hc = task & 7;
        const int tp = t0 + r - 15;
        f16x8 v = {};
        if (tp >= 0 && tp < T_)
            v = *(const f16x8*)(Xh + ((size_t)tp * B_ + b) * C_ + h * 64 + hc * 8);
        f32x4 lo, hi;
        lo[0] = (float)v[0]; lo[1] = (float)v[1];
        lo[2] = (float)v[2]; lo[3] = (float)v[3];
        hi[0] = (float)v[4]; hi[1] = (float)v[5];
        hi[2] = (float)v[6]; hi[3] = (float)v[7];
        const int c0 = (2 * hc) ^ (r & 7), c1 = (2 * hc + 1) ^ (r & 7);
        *(f32x4*)&xs[r][c0 * 4] = lo;
        *(f32x4*)&xs[r][c1 * 4] = hi;
    }
    {
        const int t = tid >> 2, kc = (tid & 3) * 8;
        const f16x8 wv =
            *(const f16x8*)(WSM + ((size_t)(t0 + t) * B_ + b) * NP + h * 32 + kc);
        f32x4 lo, hi;
        lo[0] = (float)wv[0]; lo[1] = (float)wv[1];
        lo[2] = (float)wv[2]; lo[3] = (float)wv[3];
        hi[0] = (float)wv[4]; hi[1] = (float)wv[5];
        hi[2] = (float)wv[6]; hi[3] = (float)wv[7];
        *(f32x4*)&ws[t][kc] = lo;
        *(f32x4*)&ws[t][kc + 4] = hi;
    }
    __syncthreads();

    const int s = tid & 15;
    const int tg4 = (tid >> 4) * 4;
    f32x4 acc[4] = {};
    f32x4 wc[4];

#pragma unroll
    for (int rr = 0; rr < 34; ++rr) {
        const int r = tg4 + rr;
        const f32x4 xv = *(const f32x4*)&xs[r][(s ^ (r & 7)) * 4];
#pragma unroll
        for (int i = 0; i < 4; ++i) {
            const int k = rr - i;
            if (k < 0 || k > 30) continue;
            if ((k & 3) == 0) wc[i] = *(const f32x4*)&ws[tg4 + i][k];
            acc[i] += wc[i][k & 3] * xv;
        }
    }

#pragma unroll
    for (int i = 0; i < 4; ++i) {
        const int t = t0 + tg4 + i;
        *(f32x4*)(out + ((size_t)t * B_ + b) * C_ + h * 64 + s * 4) = acc[i];
    }
}

// ---------------------------------------------------------------------------
extern "C" void kernel_launch(void* const* d_in, const int* in_sizes, int n_in,
                              void* d_out, int out_size, void* d_ws,
                              size_t ws_size, hipStream_t stream) {
    const float* X = (const float*)d_in[0];
    const float* W = (const float*)d_in[1];
    float* out = (float*)d_out;

    // workspace: Wh (1 MiB) | WSM (16 MiB) | Xh (32 MiB)  = 49 MiB
    _Float16* Wh = (_Float16*)d_ws;
    _Float16* WSM = (_Float16*)((char*)d_ws + (size_t)NP * C_ * 2);
    _Float16* Xh = (_Float16*)((char*)d_ws + (size_t)NP * C_ * 2 +
                               (size_t)M_ * NP * 2);

    cvt_inputs<<<(XCH + WCH) / 256, 256, 0, stream>>>(X, W, Xh, Wh);
    gemm_softmax<<<dim3(M_ / 128, NP / 128), 256, 0, stream>>>(Xh, Wh, WSM);
    dconv<<<dim3(T_ / 64, B_ * H_), 256, 0, stream>>>(Xh, WSM, out);
}

// Round 13
// 73.627 us; speedup vs baseline: 1.2328x; 1.0325x over previous
//
#include <hip/hip_runtime.h>
#include <cstddef>
#include <cstdint>

// Problem constants: T=2048, B=8, C=1024, H=16, K=31, P=15
constexpr int T_ = 2048;
constexpr int B_ = 8;
constexpr int C_ = 1024;
constexpr int H_ = 16;
constexpr int K_ = 31;
constexpr int P_ = 15;
constexpr int M_ = T_ * B_;   // 16384
constexpr int N_ = H_ * K_;   // 496
constexpr int NP = 512;       // padded N, slot layout n' = h*32 + k

typedef _Float16 f16x4 __attribute__((ext_vector_type(4)));
typedef _Float16 f16x8 __attribute__((ext_vector_type(8)));
typedef float f32x4 __attribute__((ext_vector_type(4)));

__device__ __forceinline__ void async_cp16(const void* g, void* l) {
    __builtin_amdgcn_global_load_lds(
        (const __attribute__((address_space(1))) void*)g,
        (__attribute__((address_space(3))) void*)l, 16, 0, 0);
}

// ---------------------------------------------------------------------------
// K0: fused convert. X -> Xh fp16; W -> Wh (512x1024 fp16, slot layout
// n' = h*32+k; k==31 rows zero). Identical to round 8 (runs ~85% HBM BW).
// ---------------------------------------------------------------------------
constexpr int XCH = M_ * C_ / 8;    // 2,097,152 f16x8 chunks
constexpr int WCH = NP * C_ / 8;    // 65,536

__global__ __launch_bounds__(256)
void cvt_inputs(const float* __restrict__ X, const float* __restrict__ W,
                _Float16* __restrict__ Xh, _Float16* __restrict__ Wh) {
    const int id = blockIdx.x * 256 + threadIdx.x;
    if (id < XCH) {
        const float4 v0 = *(const float4*)(X + (size_t)id * 8);
        const float4 v1 = *(const float4*)(X + (size_t)id * 8 + 4);
        f16x8 hv;
        hv[0] = (_Float16)v0.x; hv[1] = (_Float16)v0.y;
        hv[2] = (_Float16)v0.z; hv[3] = (_Float16)v0.w;
        hv[4] = (_Float16)v1.x; hv[5] = (_Float16)v1.y;
        hv[6] = (_Float16)v1.z; hv[7] = (_Float16)v1.w;
        *(f16x8*)(Xh + (size_t)id * 8) = hv;
    } else {
        const int j = id - XCH;
        const int n = j >> 7, sp = j & 127;
        const int h = n >> 5, k = n & 31;
        f16x8 hv = {};
        if (k < 31) {
            const float* wp = W + (size_t)(h * 31 + k) * C_ + sp * 8;
            const float4 v0 = *(const float4*)(wp);
            const float4 v1 = *(const float4*)(wp + 4);
            hv[0] = (_Float16)v0.x; hv[1] = (_Float16)v0.y;
            hv[2] = (_Float16)v0.z; hv[3] = (_Float16)v0.w;
            hv[4] = (_Float16)v1.x; hv[5] = (_Float16)v1.y;
            hv[6] = (_Float16)v1.z; hv[7] = (_Float16)v1.w;
        }
        *(f16x8*)(Wh + (size_t)n * C_ + sp * 8) = hv;
    }
}

// ---------------------------------------------------------------------------
// K1: GEMM + per-block softmax -> WSM fp16. Round-8 structure verbatim
// (counted vmcnt, A 3-deep, B 2-deep, 80 KB LDS, 2 blocks/CU, Ls overlay
// softmax). NEW: 1-D grid of 512 with XCD-partner swizzle — the 4 n-block
// partners of one A-tile land on ids {j, j+8, j+16, j+24} (same XCD under
// round-robin) so the shared A-tile is L2-resident instead of 4x L3 pulls.
// ---------------------------------------------------------------------------
__global__ __launch_bounds__(256)
void gemm_softmax(const _Float16* __restrict__ Xh,
                  const _Float16* __restrict__ Wh,
                  _Float16* __restrict__ WSM) {
    __shared__ union {
        struct { _Float16 A[3][128 * 64]; _Float16 B[2][128 * 64]; } s;
        _Float16 Ls[128 * 136];   // logits overlay (phase-disjoint), 34 KB
    } u;

    const int tid = threadIdx.x;
    const int lane = tid & 63;
    const int w = tid >> 6;
    const int wm = (w >> 1) * 64;
    const int wn = (w & 1) * 64;
    const int col = lane & 15;
    const int g = lane >> 4;

    // XCD-partner swizzle: id -> (bx, by); partners share bx (A-tile) and
    // sit 8 apart -> same XCD (round-robin id%8). Bijective on 512.
    const int id = (int)blockIdx.x;
    const int bx = (id & 7) | ((id >> 5) << 3);
    const int by = (id >> 3) & 3;
    const int m0 = bx * 128;
    const int n0 = by * 128;

    const _Float16* asrc[4];
    const _Float16* bsrc[4];
#pragma unroll
    for (int p = 0; p < 4; ++p) {
        const int ci = p * 256 + tid;
        const int r = ci >> 3, cs = ci & 7;
        const int cl = cs ^ (r & 7);
        asrc[p] = Xh + (size_t)(m0 + r) * C_ + cl * 8;
        bsrc[p] = Wh + (size_t)(n0 + r) * C_ + cl * 8;
    }

    f32x4 acc[4][4] = {};

#pragma unroll
    for (int p = 0; p < 4; ++p) {
        const int ci = p * 256 + tid;
        async_cp16(asrc[p], &u.s.A[0][ci * 8]);
    }
#pragma unroll
    for (int p = 0; p < 4; ++p) {
        const int ci = p * 256 + tid;
        async_cp16(bsrc[p], &u.s.B[0][ci * 8]);
    }
#pragma unroll
    for (int p = 0; p < 4; ++p) {
        const int ci = p * 256 + tid;
        async_cp16(asrc[p] + 64, &u.s.A[1][ci * 8]);
    }
    asm volatile("s_waitcnt vmcnt(4)" ::: "memory");
    __builtin_amdgcn_s_barrier();
    __builtin_amdgcn_sched_barrier(0);

    for (int t = 0; t < 16; ++t) {
        const int ca = t % 3, cb = t & 1;
        if (t < 15) {
            const int k1 = (t + 1) * 64;
#pragma unroll
            for (int p = 0; p < 4; ++p) {
                const int ci = p * 256 + tid;
                async_cp16(bsrc[p] + k1, &u.s.B[cb ^ 1][ci * 8]);
            }
        }
        if (t < 14) {
            const int k2 = (t + 2) * 64;
            const int ca2 = (t + 2) % 3;
#pragma unroll
            for (int p = 0; p < 4; ++p) {
                const int ci = p * 256 + tid;
                async_cp16(asrc[p] + k2, &u.s.A[ca2][ci * 8]);
            }
        }

        f16x8 a[2][4], b[2][4];
#pragma unroll
        for (int kk = 0; kk < 2; ++kk) {
#pragma unroll
            for (int mf = 0; mf < 4; ++mf) {
                const int row = wm + mf * 16 + col;
                const int c = ((kk << 2) | g) ^ (row & 7);
                a[kk][mf] = *(const f16x8*)&u.s.A[ca][row * 64 + c * 8];
            }
#pragma unroll
            for (int nf = 0; nf < 4; ++nf) {
                const int row = wn + nf * 16 + col;
                const int c = ((kk << 2) | g) ^ (row & 7);
                b[kk][nf] = *(const f16x8*)&u.s.B[cb][row * 64 + c * 8];
            }
        }
#pragma unroll
        for (int kk = 0; kk < 2; ++kk)
#pragma unroll
            for (int nf = 0; nf < 4; ++nf)
#pragma unroll
                for (int mf = 0; mf < 4; ++mf)
                    acc[mf][nf] = __builtin_amdgcn_mfma_f32_16x16x32_f16(
                        a[kk][mf], b[kk][nf], acc[mf][nf], 0, 0, 0);

        if (t < 14) {
            asm volatile("s_waitcnt vmcnt(4)" ::: "memory");
        } else {
            asm volatile("s_waitcnt vmcnt(0)" ::: "memory");
        }
        __builtin_amdgcn_s_barrier();
        __builtin_amdgcn_sched_barrier(0);
    }

    // ---- dump logits to overlay: Ls[row][nl], stride 136 ----
    const int rb = g * 4;
#pragma unroll
    for (int nf = 0; nf < 4; ++nf) {
        const int nl = wn + nf * 16 + col;
#pragma unroll
        for (int mf = 0; mf < 4; ++mf) {
            const int row = wm + mf * 16 + rb;
#pragma unroll
            for (int r = 0; r < 4; ++r)
                u.Ls[(row + r) * 136 + nl] = (_Float16)acc[mf][nf][r];
        }
    }
    __syncthreads();

    // ---- softmax: 512 (row, head-local) tasks, 2 per thread ----
#pragma unroll
    for (int p = 0; p < 2; ++p) {
        const int task = tid + p * 256;
        const int row = task >> 2, hl = task & 3;
        const _Float16* lp = &u.Ls[row * 136 + hl * 32];
        float v[32];
#pragma unroll
        for (int c = 0; c < 4; ++c) {
            const f16x8 ch = *(const f16x8*)(lp + c * 8);
#pragma unroll
            for (int e = 0; e < 8; ++e) v[c * 8 + e] = (float)ch[e];
        }
        float mx = v[0];
#pragma unroll
        for (int k = 1; k < 31; ++k) mx = fmaxf(mx, v[k]);
        float ssum = 0.f;
#pragma unroll
        for (int k = 0; k < 31; ++k) { v[k] = __expf(v[k] - mx); ssum += v[k]; }
        const float inv = 1.f / ssum;
        _Float16* op = WSM + (size_t)(m0 + row) * NP + n0 + hl * 32;
#pragma unroll
        for (int c = 0; c < 4; ++c) {
            f16x8 ov;
#pragma unroll
            for (int e = 0; e < 8; ++e) {
                const int k = c * 8 + e;
                ov[e] = (k < 31) ? (_Float16)(v[k] * inv) : (_Float16)0.f;
            }
            *(f16x8*)(op + c * 8) = ov;
        }
    }
}

// ---------------------------------------------------------------------------
// K2: depthwise dynamic conv, x read as fp16 (Xh). Identical to round 8.
// ---------------------------------------------------------------------------
__global__ __launch_bounds__(256)
void dconv(const _Float16* __restrict__ Xh, const _Float16* __restrict__ WSM,
           float* __restrict__ out) {
    __shared__ float xs[94][64];
    __shared__ float ws[64][36];

    const int tid = threadIdx.x;
    const int t0 = blockIdx.x * 64;
    const int bh = (int)blockIdx.y;
    const int b = bh >> 4, h = bh & 15;

    for (int task = tid; task < 94 * 8; task += 256) {
        const int r = task >> 3, hc = task & 7;
        const int tp = t0 + r - 15;
        f16x8 v = {};
        if (tp >= 0 && tp < T_)
            v = *(const f16x8*)(Xh + ((size_t)tp * B_ + b) * C_ + h * 64 + hc * 8);
        f32x4 lo, hi;
        lo[0] = (float)v[0]; lo[1] = (float)v[1];
        lo[2] = (float)v[2]; lo[3] = (float)v[3];
        hi[0] = (float)v[4]; hi[1] = (float)v[5];
        hi[2] = (float)v[6]; hi[3] = (float)v[7];
        const int c0 = (2 * hc) ^ (r & 7), c1 = (2 * hc + 1) ^ (r & 7);
        *(f32x4*)&xs[r][c0 * 4] = lo;
        *(f32x4*)&xs[r][c1 * 4] = hi;
    }
    {
        const int t = tid >> 2, kc = (tid & 3) * 8;
        const f16x8 wv =
            *(const f16x8*)(WSM + ((size_t)(t0 + t) * B_ + b) * NP + h * 32 + kc);
        f32x4 lo, hi;
        lo[0] = (float)wv[0]; lo[1] = (float)wv[1];
        lo[2] = (float)wv[2]; lo[3] = (float)wv[3];
        hi[0] = (float)wv[4]; hi[1] = (float)wv[5];
        hi[2] = (float)wv[6]; hi[3] = (float)wv[7];
        *(f32x4*)&ws[t][kc] = lo;
        *(f32x4*)&ws[t][kc + 4] = hi;
    }
    __syncthreads();

    const int s = tid & 15;
    const int tg4 = (tid >> 4) * 4;
    f32x4 acc[4] = {};
    f32x4 wc[4];

#pragma unroll
    for (int rr = 0; rr < 34; ++rr) {
        const int r = tg4 + rr;
        const f32x4 xv = *(const f32x4*)&xs[r][(s ^ (r & 7)) * 4];
#pragma unroll
        for (int i = 0; i < 4; ++i) {
            const int k = rr - i;
            if (k < 0 || k > 30) continue;
            if ((k & 3) == 0) wc[i] = *(const f32x4*)&ws[tg4 + i][k];
            acc[i] += wc[i][k & 3] * xv;
        }
    }

#pragma unroll
    for (int i = 0; i < 4; ++i) {
        const int t = t0 + tg4 + i;
        *(f32x4*)(out + ((size_t)t * B_ + b) * C_ + h * 64 + s * 4) = acc[i];
    }
}

// ---------------------------------------------------------------------------
extern "C" void kernel_launch(void* const* d_in, const int* in_sizes, int n_in,
                              void* d_out, int out_size, void* d_ws,
                              size_t ws_size, hipStream_t stream) {
    const float* X = (const float*)d_in[0];
    const float* W = (const float*)d_in[1];
    float* out = (float*)d_out;

    // workspace: Wh (1 MiB) | WSM (16 MiB) | Xh (32 MiB)  = 49 MiB
    _Float16* Wh = (_Float16*)d_ws;
    _Float16* WSM = (_Float16*)((char*)d_ws + (size_t)NP * C_ * 2);
    _Float16* Xh = (_Float16*)((char*)d_ws + (size_t)NP * C_ * 2 +
                               (size_t)M_ * NP * 2);

    cvt_inputs<<<(XCH + WCH) / 256, 256, 0, stream>>>(X, W, Xh, Wh);
    gemm_softmax<<<512, 256, 0, stream>>>(Xh, Wh, WSM);
    dconv<<<dim3(T_ / 64, B_ * H_), 256, 0, stream>>>(Xh, WSM, out);
}